// Round 1
// baseline (1264.868 us; speedup 1.0000x reference)
//
#include <hip/hip_runtime.h>
#include <hip/hip_bf16.h>

#define B_ 256
#define D_ 512
#define E_ 512
#define K_ 154

typedef __attribute__((ext_vector_type(8))) short short8;
typedef __attribute__((ext_vector_type(4))) float f32x4;

__device__ __forceinline__ unsigned short f2bf(float f) {
    unsigned u = __float_as_uint(f);
    u = (u + 0x7fffu + ((u >> 16) & 1u)) >> 16;
    return (unsigned short)u;
}

// ---------------- kernel 0: zero logits (f64) and out (f32) ----------------
__global__ void k_zero(double* __restrict__ logits, float* __restrict__ out) {
    int i = blockIdx.x * 256 + threadIdx.x;   // 512*256 = 131072 = 256*512
    logits[i] = 0.0;
    out[i] = 0.0f;
}

// ---------------- kernel 1: gate logits, fp64, d-split partial sums --------
__global__ __launch_bounds__(512) void k_gate(const float* __restrict__ x,
                                              const float* __restrict__ gw,
                                              double* __restrict__ logits) {
    const int tg = blockIdx.x;   // 0..31 : 8 tokens each
    const int ds = blockIdx.y;   // 0..7  : 64 d each
    const int e  = threadIdx.x;  // 0..511
    __shared__ double xs[8][64];
    const int t0 = tg * 8, d0 = ds * 64;
    {
        int t = threadIdx.x >> 6, d = threadIdx.x & 63;
        xs[t][d] = (double)x[(t0 + t) * D_ + d0 + d];
    }
    __syncthreads();
    double acc[8] = {0, 0, 0, 0, 0, 0, 0, 0};
    const float4* wrow4 = (const float4*)(gw + e * D_ + d0);
    #pragma unroll 4
    for (int j4 = 0; j4 < 16; ++j4) {
        float4 w4 = wrow4[j4];
        double w0 = (double)w4.x, w1 = (double)w4.y, w2 = (double)w4.z, w3 = (double)w4.w;
        #pragma unroll
        for (int t = 0; t < 8; ++t) {
            acc[t] = fma(xs[t][j4 * 4 + 0], w0, acc[t]);
            acc[t] = fma(xs[t][j4 * 4 + 1], w1, acc[t]);
            acc[t] = fma(xs[t][j4 * 4 + 2], w2, acc[t]);
            acc[t] = fma(xs[t][j4 * 4 + 3], w3, acc[t]);
        }
    }
    #pragma unroll
    for (int t = 0; t < 8; ++t)
        atomicAdd(&logits[(t0 + t) * E_ + e], acc[t]);
}

// ---------------- kernel 2: exact top-k (rank) + fp64 softmax + x->bf16 ----
__global__ __launch_bounds__(512) void k_topk(const double* __restrict__ logits,
                                              const float* __restrict__ gb,
                                              const float* __restrict__ x,
                                              float* __restrict__ wfull,
                                              unsigned short* __restrict__ xb) {
    const int b = blockIdx.x;
    const int e = threadIdx.x;
    __shared__ double vals[E_];
    __shared__ double red[512];
    double v = logits[b * E_ + e] + (double)gb[e];
    vals[e] = v;
    xb[b * D_ + e] = f2bf(x[b * D_ + e]);   // D_ == E_ == 512
    __syncthreads();
    int cnt = 0;
    double m = -1.0e300;
    for (int j = 0; j < E_; ++j) {
        double vj = vals[j];
        m = fmax(m, vj);
        cnt += (vj > v || (vj == v && j < e)) ? 1 : 0;
    }
    // rank < K  <=>  selected by stable top-k (ties -> lower index)
    double p = (cnt < K_) ? exp(v - m) : 0.0;
    red[e] = p;
    __syncthreads();
    for (int s = 256; s > 0; s >>= 1) {
        if (e < s) red[e] += red[e + s];
        __syncthreads();
    }
    wfull[b * E_ + e] = (float)(p / red[0]);
}

// ---------------- kernel 3: main contraction, HBM-streaming MFMA ----------
// grid 512 = 8 n-tiles x 64 expert-groups(8 experts); block 256 (4 waves)
__global__ __launch_bounds__(256, 2) void k_moe(const unsigned short* __restrict__ xb,
                                                const float* __restrict__ wfull,
                                                const float* __restrict__ tiles,
                                                float* __restrict__ out) {
    const int nt = blockIdx.x & 7;
    const int g  = blockIdx.x >> 3;
    const int n0 = nt * 64;
    const int e0 = g * 8;
    const int tid  = threadIdx.x;
    const int wv   = tid >> 6;
    const int lane = tid & 63;
    const int m0   = wv * 64;
    const int quad = lane >> 4;
    const int l16  = lane & 15;

    // B tile: 4 experts x 64 n x 64 k bf16, k-stride 72 (16B-aligned rows, 2-way banks only)
    __shared__ __align__(16) unsigned short Bs[4 * 64 * 72];
    __shared__ float ws[8][B_];

    for (int i = tid; i < 8 * B_; i += 256)
        ws[i >> 8][i & 255] = wfull[(i & 255) * E_ + e0 + (i >> 8)];

    f32x4 Ct[4][4];
    #pragma unroll
    for (int mi = 0; mi < 4; ++mi)
        #pragma unroll
        for (int ni = 0; ni < 4; ++ni)
            Ct[mi][ni] = (f32x4){0.f, 0.f, 0.f, 0.f};

    for (int p = 0; p < 2; ++p) {
        const int ep = e0 + p * 4;
        for (int kc = 0; kc < 8; ++kc) {
            const int k0 = kc * 64;
            __syncthreads();   // prior chunk's readers done (also covers ws stage, iter 0)
            // stage 4 experts' [64n x 64k] fp32 -> bf16 LDS; coalesced 16B lane loads
            #pragma unroll
            for (int j = 0; j < 16; ++j) {
                int fi = (j * 256 + tid) * 4;        // float index in 16384-elem chunk
                int k  = fi & 63;
                int n  = (fi >> 6) & 63;
                int el = fi >> 12;
                const float4* src = (const float4*)(tiles + ((ep + el) * D_ + (n0 + n)) * D_ + k0 + k);
                float4 f = *src;
                ushort4 h = make_ushort4(f2bf(f.x), f2bf(f.y), f2bf(f.z), f2bf(f.w));
                *(ushort4*)&Bs[(el * 64 + n) * 72 + k] = h;
            }
            __syncthreads();
            // A fragments direct from L2-resident xb: A[m = l16][k = quad*8 + j]
            short8 A[4][2];
            #pragma unroll
            for (int mi = 0; mi < 4; ++mi)
                #pragma unroll
                for (int ks = 0; ks < 2; ++ks)
                    A[mi][ks] = *(const short8*)&xb[(m0 + mi * 16 + l16) * D_ + k0 + ks * 32 + quad * 8];

            #pragma unroll
            for (int el = 0; el < 4; ++el) {
                f32x4 Ce[4][4];
                #pragma unroll
                for (int mi = 0; mi < 4; ++mi)
                    #pragma unroll
                    for (int ni = 0; ni < 4; ++ni)
                        Ce[mi][ni] = (f32x4){0.f, 0.f, 0.f, 0.f};
                #pragma unroll
                for (int ks = 0; ks < 2; ++ks) {
                    short8 Bf[4];
                    #pragma unroll
                    for (int ni = 0; ni < 4; ++ni)
                        Bf[ni] = *(const short8*)&Bs[(el * 64 + ni * 16 + l16) * 72 + ks * 32 + quad * 8];
                    #pragma unroll
                    for (int mi = 0; mi < 4; ++mi)
                        #pragma unroll
                        for (int ni = 0; ni < 4; ++ni)
                            Ce[mi][ni] = __builtin_amdgcn_mfma_f32_16x16x32_bf16(
                                A[mi][ks], Bf[ni], Ce[mi][ni], 0, 0, 0);
                }
                // C/D layout: col = l16 (n), row = quad*4 + reg  -> scale by w[row, e]
                const float* wrow = ws[p * 4 + el];
                #pragma unroll
                for (int mi = 0; mi < 4; ++mi) {
                    const int rbase = m0 + mi * 16 + quad * 4;
                    float w0 = wrow[rbase + 0], w1 = wrow[rbase + 1];
                    float w2 = wrow[rbase + 2], w3 = wrow[rbase + 3];
                    #pragma unroll
                    for (int ni = 0; ni < 4; ++ni) {
                        Ct[mi][ni].x += w0 * Ce[mi][ni].x;
                        Ct[mi][ni].y += w1 * Ce[mi][ni].y;
                        Ct[mi][ni].z += w2 * Ce[mi][ni].z;
                        Ct[mi][ni].w += w3 * Ce[mi][ni].w;
                    }
                }
            }
        }
    }
    #pragma unroll
    for (int mi = 0; mi < 4; ++mi)
        #pragma unroll
        for (int ni = 0; ni < 4; ++ni) {
            const int row = m0 + mi * 16 + quad * 4;
            const int col = n0 + ni * 16 + l16;
            unsafeAtomicAdd(&out[(row + 0) * D_ + col], Ct[mi][ni].x);
            unsafeAtomicAdd(&out[(row + 1) * D_ + col], Ct[mi][ni].y);
            unsafeAtomicAdd(&out[(row + 2) * D_ + col], Ct[mi][ni].z);
            unsafeAtomicAdd(&out[(row + 3) * D_ + col], Ct[mi][ni].w);
        }
}

extern "C" void kernel_launch(void* const* d_in, const int* in_sizes, int n_in,
                              void* d_out, int out_size, void* d_ws, size_t ws_size,
                              hipStream_t stream) {
    const float* x     = (const float*)d_in[0];
    const float* gw    = (const float*)d_in[1];
    const float* gb    = (const float*)d_in[2];
    const float* tiles = (const float*)d_in[3];
    float* out = (float*)d_out;

    // ws layout: logits f64 (1 MB) | wfull f32 (512 KB) | xb bf16 (256 KB)
    double* logits      = (double*)d_ws;
    float* wfull        = (float*)((char*)d_ws + (size_t)B_ * E_ * sizeof(double));
    unsigned short* xb  = (unsigned short*)((char*)d_ws + (size_t)B_ * E_ * (sizeof(double) + sizeof(float)));

    k_zero<<<512, 256, 0, stream>>>(logits, out);
    k_gate<<<dim3(32, 8), 512, 0, stream>>>(x, gw, logits);
    k_topk<<<256, 512, 0, stream>>>(logits, gb, x, wfull, xb);
    k_moe<<<512, 256, 0, stream>>>(xb, wfull, tiles, out);
}

// Round 2
// 1093.782 us; speedup vs baseline: 1.1564x; 1.1564x over previous
//
#include <hip/hip_runtime.h>
#include <hip/hip_bf16.h>

#define B_ 256
#define D_ 512
#define E_ 512
#define K_ 154

typedef __attribute__((ext_vector_type(8))) short short8;
typedef __attribute__((ext_vector_type(4))) float f32x4;

__device__ __forceinline__ unsigned short f2bf(float f) {
    unsigned u = __float_as_uint(f);
    u = (u + 0x7fffu + ((u >> 16) & 1u)) >> 16;
    return (unsigned short)u;
}

// ---------------- kernel 1: gate logits, fp64, LDS-tiled & coalesced -------
// grid (32 token-groups x 8 expert-groups), block 512. Each thread owns one
// (token, expert) pair; all global reads staged coalesced through LDS.
__global__ __launch_bounds__(512) void k_gate(const float* __restrict__ x,
                                              const float* __restrict__ gw,
                                              double* __restrict__ logits) {
    const int tg = blockIdx.x;   // 0..31 : 8 tokens
    const int eg = blockIdx.y;   // 0..7  : 64 experts
    const int tid = threadIdx.x;
    const int t0 = tg * 8, e0 = eg * 64;
    __shared__ double xs[8][512];     // 32 KB
    __shared__ float gws[64][65];     // 16.6 KB, +1 pad -> 2-way banks only
    // stage x[8][512] -> f64, coalesced (512B segments)
    #pragma unroll
    for (int i = 0; i < 8; ++i) {
        int j = i * 512 + tid;
        xs[j >> 9][j & 511] = (double)x[(t0 + (j >> 9)) * D_ + (j & 511)];
    }
    const int e = tid & 63, tl = tid >> 6;   // tl 0..7
    double acc = 0.0;
    for (int dc = 0; dc < 8; ++dc) {
        __syncthreads();   // covers xs stage (dc=0) and prior gws readers
        // stage gw[64 experts][64 d] coalesced (256B segments)
        #pragma unroll
        for (int i = 0; i < 8; ++i) {
            int j = i * 512 + tid;
            gws[j >> 6][j & 63] = gw[(e0 + (j >> 6)) * D_ + dc * 64 + (j & 63)];
        }
        __syncthreads();
        #pragma unroll 8
        for (int d = 0; d < 64; ++d)
            acc = fma((double)gws[e][d], xs[tl][dc * 64 + d], acc);
    }
    logits[(t0 + tl) * E_ + e0 + e] = acc;   // direct store, no atomics
}

// ---------------- kernel 2: exact top-k (rank) + fp64 softmax + x->bf16 ----
__global__ __launch_bounds__(512) void k_topk(const double* __restrict__ logits,
                                              const float* __restrict__ gb,
                                              const float* __restrict__ x,
                                              float* __restrict__ wT,
                                              unsigned short* __restrict__ xb) {
    const int b = blockIdx.x;
    const int e = threadIdx.x;
    __shared__ double vals[E_];
    __shared__ double red[512];
    double v = logits[b * E_ + e] + (double)gb[e];
    vals[e] = v;
    xb[b * D_ + e] = f2bf(x[b * D_ + e]);   // D_ == E_ == 512
    __syncthreads();
    int cnt = 0;
    double m = -1.0e300;
    for (int j = 0; j < E_; ++j) {
        double vj = vals[j];
        m = fmax(m, vj);
        cnt += (vj > v || (vj == v && j < e)) ? 1 : 0;
    }
    // rank < K  <=>  selected by stable top-k (ties -> lower index)
    double p = (cnt < K_) ? exp(v - m) : 0.0;
    red[e] = p;
    __syncthreads();
    for (int s = 256; s > 0; s >>= 1) {
        if (e < s) red[e] += red[e + s];
        __syncthreads();
    }
    wT[e * B_ + b] = (float)(p / red[0]);   // transposed for k_moe staging
}

// ---------------- kernel 3: main contraction, HBM-streaming MFMA ----------
// grid 1024 = 16 n-tiles(32) x 64 expert-groups(8); block 256 (4 waves).
// Per-wave out tile 64m x 32n -> Ct[4][2] (32 VGPR) + Ce[4][2] (32) : no spill.
__global__ __launch_bounds__(256, 3) void k_moe(const unsigned short* __restrict__ xb,
                                                const float* __restrict__ wT,
                                                const float* __restrict__ tiles,
                                                float* __restrict__ out) {
    const int nt = blockIdx.x & 15;
    const int g  = blockIdx.x >> 4;
    const int n0 = nt * 32;
    const int e0 = g * 8;
    const int tid  = threadIdx.x;
    const int wv   = tid >> 6;
    const int lane = tid & 63;
    const int m0   = wv * 64;
    const int quad = lane >> 4;
    const int l16  = lane & 15;

    // B tile: 4 experts x 32 n x 64 k bf16, k-stride 72 (16B-aligned rows)
    __shared__ __align__(16) unsigned short Bs[4 * 32 * 72];   // 18 KB
    __shared__ float ws[8][B_];                                // 8 KB

    #pragma unroll
    for (int i = 0; i < 8; ++i) {
        int idx = i * 256 + tid;
        ws[idx >> 8][idx & 255] = wT[(e0 + (idx >> 8)) * B_ + (idx & 255)];
    }

    f32x4 Ct[4][2];
    #pragma unroll
    for (int mi = 0; mi < 4; ++mi)
        #pragma unroll
        for (int ni = 0; ni < 2; ++ni)
            Ct[mi][ni] = (f32x4){0.f, 0.f, 0.f, 0.f};

    for (int p = 0; p < 2; ++p) {
        const int ep = e0 + p * 4;
        for (int kc = 0; kc < 8; ++kc) {
            const int k0 = kc * 64;
            __syncthreads();   // prior chunk's readers done (covers ws, iter 0)
            // stage 4 experts' [32n x 64k] fp32 -> bf16; coalesced float4 loads
            #pragma unroll
            for (int i = 0; i < 8; ++i) {
                int fi = (i * 256 + tid) * 4;       // float idx in 8192-chunk
                int k  = fi & 63;
                int n  = (fi >> 6) & 31;
                int el = fi >> 11;
                const float4 f = *(const float4*)(tiles + ((ep + el) * D_ + (n0 + n)) * D_ + k0 + k);
                *(ushort4*)&Bs[(el * 32 + n) * 72 + k] =
                    make_ushort4(f2bf(f.x), f2bf(f.y), f2bf(f.z), f2bf(f.w));
            }
            __syncthreads();
            // A fragments direct from L2-resident xb: A[m = l16][k = quad*8 + j]
            short8 A[4][2];
            #pragma unroll
            for (int mi = 0; mi < 4; ++mi)
                #pragma unroll
                for (int ks = 0; ks < 2; ++ks)
                    A[mi][ks] = *(const short8*)&xb[(m0 + mi * 16 + l16) * D_ + k0 + ks * 32 + quad * 8];

            #pragma unroll
            for (int el = 0; el < 4; ++el) {
                f32x4 Ce[4][2];
                #pragma unroll
                for (int mi = 0; mi < 4; ++mi)
                    #pragma unroll
                    for (int ni = 0; ni < 2; ++ni)
                        Ce[mi][ni] = (f32x4){0.f, 0.f, 0.f, 0.f};
                #pragma unroll
                for (int ks = 0; ks < 2; ++ks) {
                    short8 Bf[2];
                    #pragma unroll
                    for (int ni = 0; ni < 2; ++ni)
                        Bf[ni] = *(const short8*)&Bs[(el * 32 + ni * 16 + l16) * 72 + ks * 32 + quad * 8];
                    #pragma unroll
                    for (int mi = 0; mi < 4; ++mi)
                        #pragma unroll
                        for (int ni = 0; ni < 2; ++ni)
                            Ce[mi][ni] = __builtin_amdgcn_mfma_f32_16x16x32_bf16(
                                A[mi][ks], Bf[ni], Ce[mi][ni], 0, 0, 0);
                }
                // C/D layout: col = l16 (n), row = quad*4 + reg -> scale by w[row]
                const float* wrow = ws[p * 4 + el];
                #pragma unroll
                for (int mi = 0; mi < 4; ++mi) {
                    const int rbase = m0 + mi * 16 + quad * 4;
                    float w0 = wrow[rbase + 0], w1 = wrow[rbase + 1];
                    float w2 = wrow[rbase + 2], w3 = wrow[rbase + 3];
                    #pragma unroll
                    for (int ni = 0; ni < 2; ++ni) {
                        Ct[mi][ni].x += w0 * Ce[mi][ni].x;
                        Ct[mi][ni].y += w1 * Ce[mi][ni].y;
                        Ct[mi][ni].z += w2 * Ce[mi][ni].z;
                        Ct[mi][ni].w += w3 * Ce[mi][ni].w;
                    }
                }
            }
        }
    }
    #pragma unroll
    for (int mi = 0; mi < 4; ++mi)
        #pragma unroll
        for (int ni = 0; ni < 2; ++ni) {
            const int row = m0 + mi * 16 + quad * 4;
            const int col = n0 + ni * 16 + l16;
            unsafeAtomicAdd(&out[(row + 0) * D_ + col], Ct[mi][ni].x);
            unsafeAtomicAdd(&out[(row + 1) * D_ + col], Ct[mi][ni].y);
            unsafeAtomicAdd(&out[(row + 2) * D_ + col], Ct[mi][ni].z);
            unsafeAtomicAdd(&out[(row + 3) * D_ + col], Ct[mi][ni].w);
        }
}

extern "C" void kernel_launch(void* const* d_in, const int* in_sizes, int n_in,
                              void* d_out, int out_size, void* d_ws, size_t ws_size,
                              hipStream_t stream) {
    const float* x     = (const float*)d_in[0];
    const float* gw    = (const float*)d_in[1];
    const float* gb    = (const float*)d_in[2];
    const float* tiles = (const float*)d_in[3];
    float* out = (float*)d_out;

    // ws layout: logits f64 (1 MB) | wT f32 (512 KB) | xb bf16 (256 KB)
    double* logits      = (double*)d_ws;
    float* wT           = (float*)((char*)d_ws + (size_t)B_ * E_ * sizeof(double));
    unsigned short* xb  = (unsigned short*)((char*)d_ws + (size_t)B_ * E_ * (sizeof(double) + sizeof(float)));

    hipMemsetAsync(out, 0, (size_t)out_size * sizeof(float), stream);
    k_gate<<<dim3(32, 8), 512, 0, stream>>>(x, gw, logits);
    k_topk<<<256, 512, 0, stream>>>(logits, gb, x, wT, xb);
    k_moe<<<1024, 256, 0, stream>>>(xb, wT, tiles, out);
}